// Round 14
// baseline (7038.231 us; speedup 1.0000x reference)
//
#include <hip/hip_runtime.h>

#define T_STEPS 8192
#define BATCH   128
#define HID     96
#define BT      4                  // batches per block
#define NBLK    (BATCH / BT)       // 32 blocks

typedef unsigned int u32;
typedef u32   u32x4 __attribute__((ext_vector_type(4)));
typedef float f32x4 __attribute__((ext_vector_type(4)));
typedef __fp16 h2_t __attribute__((ext_vector_type(2)));

__device__ __forceinline__ u32 pk2(float a, float b) {
    return __builtin_bit_cast(u32, __builtin_amdgcn_cvt_pkrtz(a, b));
}
__device__ __forceinline__ float fast_sigmoid(float v) {
    return __builtin_amdgcn_rcpf(1.0f + __expf(-v));
}
__device__ __forceinline__ float fast_tanh(float v) {   // 2*sigmoid(2v)-1
    return fmaf(2.0f, __builtin_amdgcn_rcpf(1.0f + __expf(-2.0f * v)), -1.0f);
}

// D = A*B + C ; A from VGPR, B from AGPR (zero read-back), C/D in VGPR.
#define MFMA(ACC, AF, BF) \
    asm("v_mfma_f32_16x16x32_f16 %0, %1, %2, %0" : "+v"(ACC) : "v"(AF), "a"(BF))

// ---- prepack W_hh -> f16 MFMA B-frags, thread-major (R12 layout, verified) ----
__global__ void prepack_kernel(const float* __restrict__ W_hh, u32* __restrict__ wpk) {
    const int i = blockIdx.x * blockDim.x + threadIdx.x;   // u32 index
    if (i < 384 * 48) {
        const int r   = i & 3;
        const int u4  = i >> 2;
        const int tid = u4 / 12;
        const int f   = u4 % 12;
        const int g = f / 3, s = f % 3;
        const int l = tid & 63, u = tid >> 6;
        const int n = g * HID + u * 16 + (l & 15);
        const int k = s * 32 + ((l >> 4) & 3) * 8 + 2 * r;
        wpk[i] = pk2(W_hh[n * HID + k], W_hh[n * HID + k + 1]);
    }
}

__global__ __attribute__((amdgpu_flat_work_group_size(384, 384), amdgpu_waves_per_eu(1, 2)))
void lstm_mfma_kernel(const float* __restrict__ x,
                      const float* __restrict__ W_ih,
                      const float* __restrict__ b_ih,
                      const float* __restrict__ b_hh,
                      const float* __restrict__ W_fc,
                      const float* __restrict__ b_fc,
                      const u32x4* __restrict__ wpk4,
                      float* __restrict__ out)
{
    const int bo  = blockIdx.x * BT;
    const int tid = threadIdx.x;            // 0..383, 6 worker waves (no FC wave)
    const int l = tid & 63, u = tid >> 6;

    // h state: rows = 4 batches, 128-col rows (256B => bank-aligned), XOR-block swizzle
    __shared__ __align__(16) __fp16 hbuf[2][BT][128];
    __shared__ __align__(16) float  xs[2][BT];       // staged x
    __shared__ __align__(16) float  fcp[2][BT][8];   // FC partials [buf][batch][wave]

    for (int i = tid; i < 2 * BT * 128 / 2; i += 384) ((u32*)hbuf)[i] = 0u;
    if (tid < 64) ((float*)fcp)[tid] = 0.0f;
    if (tid < BT) xs[0][tid] = x[bo + tid];

    const int j  = u * 16 + (l & 15);       // this lane's unit (epilogue)
    const int m  = l >> 4;                  // this lane's batch slot (epilogue)
    const int mA = (l & 15) & 3;            // batch row this lane READS for A (dup trick)
    const int lg = l >> 4;                  // k-subgroup for A

    // B-frags: load once, pin into AGPRs (R12-proven: FETCH 4.4MB => loop load-free)
    const u32x4* wp = wpk4 + tid * 12;
    u32x4 b0 = wp[0], b1 = wp[1], b2  = wp[2],  b3  = wp[3];
    u32x4 b4 = wp[4], b5 = wp[5], b6  = wp[6],  b7  = wp[7];
    u32x4 b8 = wp[8], b9 = wp[9], b10 = wp[10], b11 = wp[11];
    asm volatile("" : "+a"(b0));  asm volatile("" : "+a"(b1));
    asm volatile("" : "+a"(b2));  asm volatile("" : "+a"(b3));
    asm volatile("" : "+a"(b4));  asm volatile("" : "+a"(b5));
    asm volatile("" : "+a"(b6));  asm volatile("" : "+a"(b7));
    asm volatile("" : "+a"(b8));  asm volatile("" : "+a"(b9));
    asm volatile("" : "+a"(b10)); asm volatile("" : "+a"(b11));

    f32x4 wih4 = { W_ih[0*HID+j], W_ih[1*HID+j], W_ih[2*HID+j], W_ih[3*HID+j] };
    f32x4 bs4  = { b_ih[0*HID+j] + b_hh[0*HID+j], b_ih[1*HID+j] + b_hh[1*HID+j],
                   b_ih[2*HID+j] + b_hh[2*HID+j], b_ih[3*HID+j] + b_hh[3*HID+j] };
    float wfc  = W_fc[j];
    asm volatile("" : "+v"(wih4)); asm volatile("" : "+v"(bs4));
    asm volatile("" : "+v"(wfc));
    const float bfc = b_fc[0];

    float c = 0.0f;                         // cell state for (batch m, unit j)

    // x prefetch pipeline (wave 0 lanes 0..3), distance 2
    float xrA = 0.0f, xrB = 0.0f;
    if (tid < BT) { xrA = x[1 * BATCH + bo + tid]; xrB = x[2 * BATCH + bo + tid]; }

    __syncthreads();

    for (int t = 0; t < T_STEPS; ++t) {
        const int cb = t & 1, nb = cb ^ 1;

        // A-frags, batch-duplicated rows + XOR-swizzled cols: conflict-free b128
        const __fp16* hrow = &hbuf[cb][mA][0];
        const u32x4 a0 = *(const u32x4*)(hrow + ((lg    ) ^ mA) * 8);
        const u32x4 a1 = *(const u32x4*)(hrow + ((4 + lg) ^ mA) * 8);
        const u32x4 a2 = *(const u32x4*)(hrow + ((8 + lg) ^ mA) * 8);
        const f32x4 xs4 = *(const f32x4*)&xs[cb][0];   // all 4 batches, broadcast

        // C-init: acc_g[r] = x[batch r]*wih + bias (valid in EVERY lane)
        f32x4 acc0 = xs4 * wih4[0] + bs4[0];
        f32x4 acc1 = xs4 * wih4[1] + bs4[1];
        f32x4 acc2 = xs4 * wih4[2] + bs4[2];
        f32x4 acc3 = xs4 * wih4[3] + bs4[3];

        MFMA(acc0, a0, b0); MFMA(acc1, a0, b3); MFMA(acc2, a0, b6); MFMA(acc3, a0, b9);
        MFMA(acc0, a1, b1); MFMA(acc1, a1, b4); MFMA(acc2, a1, b7); MFMA(acc3, a1, b10);
        MFMA(acc0, a2, b2); MFMA(acc1, a2, b5); MFMA(acc2, a2, b8); MFMA(acc3, a2, b11);
        asm volatile("s_nop 7\n\ts_nop 7");            // MFMA->VALU hazard guard

        // wave 0 lanes 0..3: emit out[t-1] from last step's FC partials (off hot path)
        if (u == 0 && l < BT && t > 0) {
            const float* fp = fcp[cb][l];
            const float s = ((fp[0] + fp[1]) + (fp[2] + fp[3])) + (fp[4] + fp[5]);
            out[(t - 1) * BATCH + bo + l] = s + bfc + xs[nb][l];   // xs[nb] still x[t-1]
        }

        // epilogue: ONE (batch m, unit j) per lane; select batch m from acc regs
        const float pi = (m == 0) ? acc0[0] : (m == 1) ? acc0[1] : (m == 2) ? acc0[2] : acc0[3];
        const float pf = (m == 0) ? acc1[0] : (m == 1) ? acc1[1] : (m == 2) ? acc1[2] : acc1[3];
        const float pg = (m == 0) ? acc2[0] : (m == 1) ? acc2[1] : (m == 2) ? acc2[2] : acc2[3];
        const float po = (m == 0) ? acc3[0] : (m == 1) ? acc3[1] : (m == 2) ? acc3[2] : acc3[3];

        const float gi = fast_sigmoid(pi);
        const float gf = fast_sigmoid(pf);
        const float gg = fast_tanh(pg);
        const float go = fast_sigmoid(po);
        c = fmaf(gf, c, gi * gg);
        const float hn = go * fast_tanh(c);

        // h write, XOR-block swizzle (read side uses the same XOR)
        hbuf[nb][m][((j >> 3) ^ m) * 8 + (j & 7)] = (__fp16)hn;

        // online FC: reduce hn*wfc over the 16 lanes (units) of this batch group
        float p = hn * wfc;
        p += __shfl_xor(p, 1); p += __shfl_xor(p, 2);
        p += __shfl_xor(p, 4); p += __shfl_xor(p, 8);
        if ((l & 15) == 0) fcp[nb][m][u] = p;

        // stage x[t+1] from register; refill pipeline (distance 2)
        if (tid < BT) {
            xs[nb][tid] = xrA;
            xrA = xrB;
            const int tn = (t + 3 < T_STEPS) ? (t + 3) : (T_STEPS - 1);
            xrB = x[tn * BATCH + bo + tid];
        }
        __syncthreads();
    }

    // tail: out[T-1] from the last fcp buffer
    if (u == 0 && l < BT) {
        const float* fp = fcp[T_STEPS & 1][l];
        const float s = ((fp[0] + fp[1]) + (fp[2] + fp[3])) + (fp[4] + fp[5]);
        out[(T_STEPS - 1) * BATCH + bo + l] = s + bfc + x[(T_STEPS - 1) * BATCH + bo + l];
    }
}

extern "C" void kernel_launch(void* const* d_in, const int* in_sizes, int n_in,
                              void* d_out, int out_size, void* d_ws, size_t ws_size,
                              hipStream_t stream) {
    (void)in_sizes; (void)n_in; (void)out_size; (void)ws_size;
    const float* x    = (const float*)d_in[0];
    const float* W_ih = (const float*)d_in[1];
    const float* W_hh = (const float*)d_in[2];
    const float* b_ih = (const float*)d_in[3];
    const float* b_hh = (const float*)d_in[4];
    const float* W_fc = (const float*)d_in[5];
    const float* b_fc = (const float*)d_in[6];
    float* out = (float*)d_out;
    u32* wpk = (u32*)d_ws;                          // 384*48 u32 = 73728 B

    prepack_kernel<<<dim3((384 * 48 + 255) / 256), dim3(256), 0, stream>>>(W_hh, wpk);

    lstm_mfma_kernel<<<dim3(NBLK), dim3(384), 0, stream>>>(
        x, W_ih, b_ih, b_hh, W_fc, b_fc, (const u32x4*)wpk, out);
}

// Round 15
// 7024.753 us; speedup vs baseline: 1.0019x; 1.0019x over previous
//
#include <hip/hip_runtime.h>

#define T_STEPS 8192
#define BATCH   128
#define HID     96
#define BT      16                 // batch tile per block
#define NBLK    (BATCH / BT)       // 8 blocks

typedef unsigned int u32;
typedef u32   u32x4 __attribute__((ext_vector_type(4)));
typedef float f32x4 __attribute__((ext_vector_type(4)));
typedef __fp16 h2_t __attribute__((ext_vector_type(2)));

__device__ __forceinline__ u32 pk2(float a, float b) {
    return __builtin_bit_cast(u32, __builtin_amdgcn_cvt_pkrtz(a, b));
}
__device__ __forceinline__ float fdot2u(u32 w, u32 h, float acc) {
    return __builtin_amdgcn_fdot2(__builtin_bit_cast(h2_t, w),
                                  __builtin_bit_cast(h2_t, h), acc, false);
}
__device__ __forceinline__ float fast_sigmoid(float v) {
    return __builtin_amdgcn_rcpf(1.0f + __expf(-v));
}
__device__ __forceinline__ float fast_tanh(float v) {   // 2*sigmoid(2v)-1
    return fmaf(2.0f, __builtin_amdgcn_rcpf(1.0f + __expf(-2.0f * v)), -1.0f);
}

// D = A*B + C ; A from VGPR, B from AGPR (zero read-back), C/D in VGPR.
#define MFMA(ACC, AF, BF) \
    asm("v_mfma_f32_16x16x32_f16 %0, %1, %2, %0" : "+v"(ACC) : "v"(AF), "a"(BF))

// LDS-only barrier: __syncthreads() would emit s_waitcnt vmcnt(0) and drain the
// out-store / x-load acks (~300-900 cyc) onto EVERY step's critical path -- the
// R12-R14 ~2000cyc/step mystery. All cross-wave traffic here is LDS, so
// lgkmcnt(0)+s_barrier suffices; global ops stay in flight across steps.
#define LBAR() asm volatile("s_waitcnt lgkmcnt(0)\n\ts_barrier" ::: "memory")

// ---- prepack W_hh -> f16 MFMA B-frags, thread-major (R12 layout, verified) ----
__global__ void prepack_kernel(const float* __restrict__ W_hh, u32* __restrict__ wpk) {
    const int i = blockIdx.x * blockDim.x + threadIdx.x;   // u32 index
    if (i < 384 * 48) {
        const int r   = i & 3;
        const int u4  = i >> 2;
        const int tid = u4 / 12;
        const int f   = u4 % 12;
        const int g = f / 3, s = f % 3;
        const int l = tid & 63, u = tid >> 6;
        const int n = g * HID + u * 16 + (l & 15);
        const int k = s * 32 + ((l >> 4) & 3) * 8 + 2 * r;
        wpk[i] = pk2(W_hh[n * HID + k], W_hh[n * HID + k + 1]);
    }
}

__global__ __attribute__((amdgpu_flat_work_group_size(448, 448), amdgpu_waves_per_eu(1, 2)))
void lstm_mfma_kernel(const float* __restrict__ x,
                      const float* __restrict__ W_ih,
                      const float* __restrict__ b_ih,
                      const float* __restrict__ b_hh,
                      const float* __restrict__ W_fc,
                      const float* __restrict__ b_fc,
                      const u32x4* __restrict__ wpk4,
                      float* __restrict__ out)
{
    const int bo  = blockIdx.x * BT;
    const int tid = threadIdx.x;            // 0..447: waves 0-5 workers, wave 6 FC
    const int l = tid & 63, u = tid >> 6;
    const bool isW = tid < 384;

    __shared__ __align__(16) __fp16 hbuf[2][BT][104];   // h state, row-pad 104

    for (int i = tid; i < 2 * BT * 104 / 2; i += 448) ((u32*)hbuf)[i] = 0u;

    const int jw = isW ? (u * 16 + (l & 15)) : 0;       // this lane's unit (workers)
    const int fm = l >> 2, fp = l & 3;                  // FC wave: batch, quarter

    // B-frags: load once, pin into AGPRs (R12-proven: FETCH 4.4MB, loop load-free)
    const u32x4* wp = wpk4 + (isW ? tid * 12 : 0);
    u32x4 b0 = wp[0], b1 = wp[1], b2  = wp[2],  b3  = wp[3];
    u32x4 b4 = wp[4], b5 = wp[5], b6  = wp[6],  b7  = wp[7];
    u32x4 b8 = wp[8], b9 = wp[9], b10 = wp[10], b11 = wp[11];
    asm volatile("" : "+a"(b0));  asm volatile("" : "+a"(b1));
    asm volatile("" : "+a"(b2));  asm volatile("" : "+a"(b3));
    asm volatile("" : "+a"(b4));  asm volatile("" : "+a"(b5));
    asm volatile("" : "+a"(b6));  asm volatile("" : "+a"(b7));
    asm volatile("" : "+a"(b8));  asm volatile("" : "+a"(b9));
    asm volatile("" : "+a"(b10)); asm volatile("" : "+a"(b11));

    f32x4 wih4 = { W_ih[0*HID+jw], W_ih[1*HID+jw], W_ih[2*HID+jw], W_ih[3*HID+jw] };
    f32x4 bs4  = { b_ih[0*HID+jw] + b_hh[0*HID+jw], b_ih[1*HID+jw] + b_hh[1*HID+jw],
                   b_ih[2*HID+jw] + b_hh[2*HID+jw], b_ih[3*HID+jw] + b_hh[3*HID+jw] };
    asm volatile("" : "+v"(wih4)); asm volatile("" : "+v"(bs4));
    const float bfc = b_fc[0];

    u32 wf[12];
    #pragma unroll
    for (int r = 0; r < 12; ++r)
        wf[r] = pk2(W_fc[fp * 24 + 2 * r], W_fc[fp * 24 + 2 * r + 1]);

    f32x4 c = {0.f, 0.f, 0.f, 0.f};         // cell state, 4 batches of unit jw

    // x parity registers, 2-step pipeline (NO shifting -> no per-step vmcnt drain)
    f32x4 xe = {0,0,0,0}, xo = {0,0,0,0};   // workers: x[t][4 batches], even/odd t
    float fe = 0.0f, fo = 0.0f;             // FC: x[t-1][fm], even/odd t
    if (isW) {
        xe = *(const f32x4*)(x + 0 * BATCH + bo + (l >> 4) * 4);
        xo = *(const f32x4*)(x + 1 * BATCH + bo + (l >> 4) * 4);
    } else {
        fo = x[bo + fm];                    // x[0], used by FC body at t=1
    }
    __syncthreads();

    auto body = [&](int t, f32x4& XR, float& FR) {
        const int cb = t & 1, nb = cb ^ 1;
        if (isW) {
            // A-frags: lane l holds h[batch l&15][k=(l>>4)*8 + s*32 .. +8]
            const __fp16* hrow = &hbuf[cb][l & 15][(l >> 4) * 8];
            const u32x4 a0 = *(const u32x4*)(hrow);
            const u32x4 a1 = *(const u32x4*)(hrow + 32);
            const u32x4 a2 = *(const u32x4*)(hrow + 64);
            const f32x4 xv = XR;

            f32x4 acc0 = xv * wih4[0] + bs4[0];
            f32x4 acc1 = xv * wih4[1] + bs4[1];
            f32x4 acc2 = xv * wih4[2] + bs4[2];
            f32x4 acc3 = xv * wih4[3] + bs4[3];

            MFMA(acc0, a0, b0); MFMA(acc1, a0, b3); MFMA(acc2, a0, b6); MFMA(acc3, a0, b9);
            MFMA(acc0, a1, b1); MFMA(acc1, a1, b4); MFMA(acc2, a1, b7); MFMA(acc3, a1, b10);
            MFMA(acc0, a2, b2); MFMA(acc1, a2, b5); MFMA(acc2, a2, b8); MFMA(acc3, a2, b11);
            asm volatile("s_nop 7\n\ts_nop 7");     // MFMA->VALU hazard guard

            #pragma unroll
            for (int r = 0; r < 4; ++r) {
                const float gi = fast_sigmoid(acc0[r]);
                const float gf = fast_sigmoid(acc1[r]);
                const float gg = fast_tanh(acc2[r]);
                const float go = fast_sigmoid(acc3[r]);
                c[r] = fmaf(gf, c[r], gi * gg);
                const float hn = go * fast_tanh(c[r]);
                hbuf[nb][(l >> 4) * 4 + r][jw] = (__fp16)hn;
            }
            // refill this parity's x (used at t+2); compiler emits counted wait at use
            const int tn = (t + 2 < T_STEPS) ? (t + 2) : t;
            XR = *(const f32x4*)(x + tn * BATCH + bo + (l >> 4) * 4);
        } else {
            if (t > 0) {
                const u32x4* hb = (const u32x4*)&hbuf[cb][fm][fp * 24];
                const u32x4 h0 = hb[0], h1 = hb[1], h2 = hb[2];
                float s0 = 0.f, s1 = 0.f, s2 = 0.f;
                s0 = fdot2u(wf[0], h0[0], s0); s0 = fdot2u(wf[1],  h0[1], s0);
                s0 = fdot2u(wf[2], h0[2], s0); s0 = fdot2u(wf[3],  h0[3], s0);
                s1 = fdot2u(wf[4], h1[0], s1); s1 = fdot2u(wf[5],  h1[1], s1);
                s1 = fdot2u(wf[6], h1[2], s1); s1 = fdot2u(wf[7],  h1[3], s1);
                s2 = fdot2u(wf[8], h2[0], s2); s2 = fdot2u(wf[9],  h2[1], s2);
                s2 = fdot2u(wf[10],h2[2], s2); s2 = fdot2u(wf[11], h2[3], s2);
                float s = (s0 + s1) + s2;
                s += __shfl_xor(s, 1); s += __shfl_xor(s, 2);
                if (fp == 0) out[(t - 1) * BATCH + bo + fm] = s + bfc + FR;  // fire-and-forget
            }
            const int tn = (t + 1 < T_STEPS) ? (t + 1) : (T_STEPS - 1);
            FR = x[tn * BATCH + bo + fm];           // x[t+1], used at t+2 as x[(t+2)-1]
        }
        LBAR();
    };

    for (int t2 = 0; t2 < T_STEPS; t2 += 2) {
        body(t2,     xe, fe);
        body(t2 + 1, xo, fo);
    }

    if (!isW) {     // tail: out[T-1] from h_T (in hbuf[T&1=0]) + x[T-1] (in fo)
        const u32x4* hb = (const u32x4*)&hbuf[T_STEPS & 1][fm][fp * 24];
        const u32x4 h0 = hb[0], h1 = hb[1], h2 = hb[2];
        float s0 = 0.f, s1 = 0.f, s2 = 0.f;
        s0 = fdot2u(wf[0], h0[0], s0); s0 = fdot2u(wf[1],  h0[1], s0);
        s0 = fdot2u(wf[2], h0[2], s0); s0 = fdot2u(wf[3],  h0[3], s0);
        s1 = fdot2u(wf[4], h1[0], s1); s1 = fdot2u(wf[5],  h1[1], s1);
        s1 = fdot2u(wf[6], h1[2], s1); s1 = fdot2u(wf[7],  h1[3], s1);
        s2 = fdot2u(wf[8], h2[0], s2); s2 = fdot2u(wf[9],  h2[1], s2);
        s2 = fdot2u(wf[10],h2[2], s2); s2 = fdot2u(wf[11], h2[3], s2);
        float s = (s0 + s1) + s2;
        s += __shfl_xor(s, 1); s += __shfl_xor(s, 2);
        if (fp == 0) out[(T_STEPS - 1) * BATCH + bo + fm] = s + bfc + fo;
    }
}

extern "C" void kernel_launch(void* const* d_in, const int* in_sizes, int n_in,
                              void* d_out, int out_size, void* d_ws, size_t ws_size,
                              hipStream_t stream) {
    (void)in_sizes; (void)n_in; (void)out_size; (void)ws_size;
    const float* x    = (const float*)d_in[0];
    const float* W_ih = (const float*)d_in[1];
    const float* W_hh = (const float*)d_in[2];
    const float* b_ih = (const float*)d_in[3];
    const float* b_hh = (const float*)d_in[4];
    const float* W_fc = (const float*)d_in[5];
    const float* b_fc = (const float*)d_in[6];
    float* out = (float*)d_out;
    u32* wpk = (u32*)d_ws;                          // 384*48 u32 = 73728 B

    prepack_kernel<<<dim3((384 * 48 + 255) / 256), dim3(256), 0, stream>>>(W_hh, wpk);

    lstm_mfma_kernel<<<dim3(NBLK), dim3(448), 0, stream>>>(
        x, W_ih, b_ih, b_hh, W_fc, b_fc, (const u32x4*)wpk, out);
}

// Round 16
// 4584.356 us; speedup vs baseline: 1.5353x; 1.5323x over previous
//
#include <hip/hip_runtime.h>

#define T_STEPS 8192
#define BATCH   128
#define HID     96
#define BT      8                  // batch tile per block
#define NBLK    (BATCH / BT)       // 16 blocks

typedef unsigned int u32;
typedef u32   u32x4 __attribute__((ext_vector_type(4)));
typedef float f32x4 __attribute__((ext_vector_type(4)));
typedef __fp16 h2_t __attribute__((ext_vector_type(2)));

#define L2E 1.4426950408889634f
#define K2  2.8853900817779268f   // 2*log2(e)

__device__ __forceinline__ u32 pk2(float a, float b) {
    return __builtin_bit_cast(u32, __builtin_amdgcn_cvt_pkrtz(a, b));
}
__device__ __forceinline__ float fdot2u(u32 w, u32 h, float acc) {
    return __builtin_amdgcn_fdot2(__builtin_bit_cast(h2_t, w),
                                  __builtin_bit_cast(h2_t, h), acc, false);
}
// preacts arrive PRE-SCALED by log2e (2log2e for g/cell): exp2 direct, no mul
__device__ __forceinline__ float sig2(float v) {   // sigmoid of scaled preact
    return __builtin_amdgcn_rcpf(1.0f + __builtin_amdgcn_exp2f(-v));
}
__device__ __forceinline__ float tanh2(float v) {  // tanh of 2log2e-scaled preact
    return fmaf(2.0f, __builtin_amdgcn_rcpf(1.0f + __builtin_amdgcn_exp2f(-v)), -1.0f);
}

#define MFMA(ACC, AF, BF) \
    asm("v_mfma_f32_16x16x32_f16 %0, %1, %2, %0" : "+v"(ACC) : "v"(AF), "a"(BF))

// LDS-only barrier (R15-proven correct)
#define LBAR() asm volatile("s_waitcnt lgkmcnt(0)\n\ts_barrier" ::: "memory")

// ---- prepack W_hh -> f16 MFMA B-frags (R12-verified mapping) + exp2 prescale ----
__global__ void prepack_kernel(const float* __restrict__ W_hh, u32* __restrict__ wpk) {
    const int i = blockIdx.x * blockDim.x + threadIdx.x;
    if (i < 384 * 48) {
        const int r   = i & 3;
        const int u4  = i >> 2;
        const int tid = u4 / 12;
        const int f   = u4 % 12;
        const int g = f / 3, s = f % 3;
        const int l = tid & 63, u = tid >> 6;
        const int n = g * HID + u * 16 + (l & 15);
        const int k = s * 32 + ((l >> 4) & 3) * 8 + 2 * r;
        const float sc = (g == 2) ? K2 : L2E;
        wpk[i] = pk2(W_hh[n * HID + k] * sc, W_hh[n * HID + k + 1] * sc);
    }
}

__global__ __attribute__((amdgpu_flat_work_group_size(448, 448), amdgpu_waves_per_eu(1, 2)))
void lstm_mfma_kernel(const float* __restrict__ x,
                      const float* __restrict__ W_ih,
                      const float* __restrict__ b_ih,
                      const float* __restrict__ b_hh,
                      const float* __restrict__ W_fc,
                      const float* __restrict__ b_fc,
                      const u32x4* __restrict__ wpk4,
                      float* __restrict__ out)
{
    const int bo  = blockIdx.x * BT;
    const int tid = threadIdx.x;            // waves 0-5 workers, wave 6 FC
    const int l = tid & 63, u = tid >> 6;
    const bool isW = tid < 384;
    const int lg = l >> 4;

    // rows indexed by BATCH (0-7); pad 104 f16 = 208B (16B-aligned rows)
    __shared__ __align__(16) __fp16 hbuf[2][BT][104];
    __shared__ __align__(16) float  xs[2][BT];

    for (int i = tid; i < 2 * BT * 104 / 2; i += 448) ((u32*)hbuf)[i] = 0u;
    if (tid < BT) xs[0][tid] = x[bo + tid];

    const int jw = isW ? (u * 16 + (l & 15)) : 0;

    // B-frags: load once, pin to AGPRs (R12-proven residency)
    const u32x4* wp = wpk4 + (isW ? tid * 12 : 0);
    u32x4 b0 = wp[0], b1 = wp[1], b2  = wp[2],  b3  = wp[3];
    u32x4 b4 = wp[4], b5 = wp[5], b6  = wp[6],  b7  = wp[7];
    u32x4 b8 = wp[8], b9 = wp[9], b10 = wp[10], b11 = wp[11];
    asm volatile("" : "+a"(b0));  asm volatile("" : "+a"(b1));
    asm volatile("" : "+a"(b2));  asm volatile("" : "+a"(b3));
    asm volatile("" : "+a"(b4));  asm volatile("" : "+a"(b5));
    asm volatile("" : "+a"(b6));  asm volatile("" : "+a"(b7));
    asm volatile("" : "+a"(b8));  asm volatile("" : "+a"(b9));
    asm volatile("" : "+a"(b10)); asm volatile("" : "+a"(b11));

    // x-weights / biases, prescaled per gate (i,f,o: log2e; g: 2log2e)
    f32x4 wih4 = { W_ih[0*HID+jw] * L2E, W_ih[1*HID+jw] * L2E,
                   W_ih[2*HID+jw] * K2,  W_ih[3*HID+jw] * L2E };
    f32x4 bs4  = { (b_ih[0*HID+jw] + b_hh[0*HID+jw]) * L2E,
                   (b_ih[1*HID+jw] + b_hh[1*HID+jw]) * L2E,
                   (b_ih[2*HID+jw] + b_hh[2*HID+jw]) * K2,
                   (b_ih[3*HID+jw] + b_hh[3*HID+jw]) * L2E };
    asm volatile("" : "+v"(wih4)); asm volatile("" : "+v"(bs4));
    const float bfc = b_fc[0];

    // FC wave setup: m = l&7 (batch), p = l>>3 (12-col quarter-of-8)
    const int fm = l & 7, fp = l >> 3;
    u32 wf0=0,wf1=0,wf2=0,wf3=0,wf4=0,wf5=0;
    if (!isW) {
        wf0 = pk2(W_fc[fp*12+0],  W_fc[fp*12+1]);
        wf1 = pk2(W_fc[fp*12+2],  W_fc[fp*12+3]);
        wf2 = pk2(W_fc[fp*12+4],  W_fc[fp*12+5]);
        wf3 = pk2(W_fc[fp*12+6],  W_fc[fp*12+7]);
        wf4 = pk2(W_fc[fp*12+8],  W_fc[fp*12+9]);
        wf5 = pk2(W_fc[fp*12+10], W_fc[fp*12+11]);
    }

    float c0 = 0.0f, c1 = 0.0f;             // scaled cell state, batches m0,m1
    const int m0 = lg * 2, m1 = lg * 2 + 1; // this lane's epilogue batches

    // FC x shift-chain: xO=x[t-1] (out), xC=x[t], xP=x[t+1] (staged)
    float xO = 0.f, xC = 0.f, xP = 0.f;
    if (!isW) { xC = x[bo + fm]; xP = x[BATCH + bo + fm]; }
    __syncthreads();

    for (int t = 0; t < T_STEPS; ++t) {
        const int cb = t & 1, nb = cb ^ 1;
        if (isW) {
            // x pair for this lane's batches (broadcast ds_read_b64)
            const float2 xp = *(const float2*)&xs[cb][m0];
            // A-frags: row rho holds batch (rho>>2)*2+(rho&1)
            const int arow = ((l & 15) >> 2) * 2 + ((l & 15) & 1);
            const __fp16* hrow = &hbuf[cb][arow][lg * 8];
            const u32x4 a0 = *(const u32x4*)(hrow);
            const u32x4 a1 = *(const u32x4*)(hrow + 32);
            const u32x4 a2 = *(const u32x4*)(hrow + 64);

            // C-init: rows r=0,2 -> batch m0; r=1,3 -> batch m1
            const float e00 = fmaf(xp.x, wih4[0], bs4[0]), e01 = fmaf(xp.y, wih4[0], bs4[0]);
            const float e10 = fmaf(xp.x, wih4[1], bs4[1]), e11 = fmaf(xp.y, wih4[1], bs4[1]);
            const float e20 = fmaf(xp.x, wih4[2], bs4[2]), e21 = fmaf(xp.y, wih4[2], bs4[2]);
            const float e30 = fmaf(xp.x, wih4[3], bs4[3]), e31 = fmaf(xp.y, wih4[3], bs4[3]);
            f32x4 acc0 = {e00, e01, e00, e01};
            f32x4 acc1 = {e10, e11, e10, e11};
            f32x4 acc2 = {e20, e21, e20, e21};
            f32x4 acc3 = {e30, e31, e30, e31};

            MFMA(acc0, a0, b0); MFMA(acc1, a0, b3); MFMA(acc2, a0, b6); MFMA(acc3, a0, b9);
            MFMA(acc0, a1, b1); MFMA(acc1, a1, b4); MFMA(acc2, a1, b7); MFMA(acc3, a1, b10);
            MFMA(acc0, a2, b2); MFMA(acc1, a2, b5); MFMA(acc2, a2, b8); MFMA(acc3, a2, b11);
            asm volatile("s_nop 7\n\ts_nop 7");

            // epilogue: 2 updates, STATIC acc indices (r=0,1), no divergence
            {
                const float gi = sig2(acc0[0]);
                const float gf = sig2(acc1[0]);
                const float gg = tanh2(acc2[0]);
                const float go = sig2(acc3[0]);
                c0 = fmaf(gf, c0, gi * gg * K2);
                const float hn = go * tanh2(c0);
                hbuf[nb][m0][jw] = (__fp16)hn;
            }
            {
                const float gi = sig2(acc0[1]);
                const float gf = sig2(acc1[1]);
                const float gg = tanh2(acc2[1]);
                const float go = sig2(acc3[1]);
                c1 = fmaf(gf, c1, gi * gg * K2);
                const float hn = go * tanh2(c1);
                hbuf[nb][m1][jw] = (__fp16)hn;
            }
        } else {
            if (t > 0) {
                // h_t dot W_fc: lane (fm, fp) covers 12 f16 cols
                const u32* hp = (const u32*)&hbuf[cb][fm][0] + fp * 6;
                const uint2 hA = *(const uint2*)(hp);
                const uint2 hB = *(const uint2*)(hp + 2);
                const uint2 hC = *(const uint2*)(hp + 4);
                float s0 = 0.f, s1 = 0.f, s2 = 0.f;
                s0 = fdot2u(wf0, hA.x, s0); s0 = fdot2u(wf1, hA.y, s0);
                s1 = fdot2u(wf2, hB.x, s1); s1 = fdot2u(wf3, hB.y, s1);
                s2 = fdot2u(wf4, hC.x, s2); s2 = fdot2u(wf5, hC.y, s2);
                float s = (s0 + s1) + s2;
                s += __shfl_xor(s, 8); s += __shfl_xor(s, 16); s += __shfl_xor(s, 32);
                if (fp == 0) out[(t - 1) * BATCH + bo + fm] = s + bfc + xO;  // fire-and-forget
            }
            if (fp == 0) xs[nb][fm] = xP;        // stage x[t+1]
            xO = xC; xC = xP;                    // shift chain
            const int tn = (t + 2 < T_STEPS) ? (t + 2) : (T_STEPS - 1);
            xP = x[tn * BATCH + bo + fm];
        }
        LBAR();
    }

    if (!isW) {   // tail: out[T-1] from h_T (hbuf[0]); xO = x[T-1] after last shift
        const u32* hp = (const u32*)&hbuf[T_STEPS & 1][fm][0] + fp * 6;
        const uint2 hA = *(const uint2*)(hp);
        const uint2 hB = *(const uint2*)(hp + 2);
        const uint2 hC = *(const uint2*)(hp + 4);
        float s0 = 0.f, s1 = 0.f, s2 = 0.f;
        s0 = fdot2u(wf0, hA.x, s0); s0 = fdot2u(wf1, hA.y, s0);
        s1 = fdot2u(wf2, hB.x, s1); s1 = fdot2u(wf3, hB.y, s1);
        s2 = fdot2u(wf4, hC.x, s2); s2 = fdot2u(wf5, hC.y, s2);
        float s = (s0 + s1) + s2;
        s += __shfl_xor(s, 8); s += __shfl_xor(s, 16); s += __shfl_xor(s, 32);
        if (fp == 0) out[(T_STEPS - 1) * BATCH + bo + fm] = s + bfc + xO;
    }
}

extern "C" void kernel_launch(void* const* d_in, const int* in_sizes, int n_in,
                              void* d_out, int out_size, void* d_ws, size_t ws_size,
                              hipStream_t stream) {
    (void)in_sizes; (void)n_in; (void)out_size; (void)ws_size;
    const float* x    = (const float*)d_in[0];
    const float* W_ih = (const float*)d_in[1];
    const float* W_hh = (const float*)d_in[2];
    const float* b_ih = (const float*)d_in[3];
    const float* b_hh = (const float*)d_in[4];
    const float* W_fc = (const float*)d_in[5];
    const float* b_fc = (const float*)d_in[6];
    float* out = (float*)d_out;
    u32* wpk = (u32*)d_ws;                          // 384*48 u32 = 73728 B

    prepack_kernel<<<dim3((384 * 48 + 255) / 256), dim3(256), 0, stream>>>(W_hh, wpk);

    lstm_mfma_kernel<<<dim3(NBLK), dim3(448), 0, stream>>>(
        x, W_ih, b_ih, b_hh, W_fc, b_fc, (const u32x4*)wpk, out);
}

// Round 17
// 4190.403 us; speedup vs baseline: 1.6796x; 1.0940x over previous
//
#include <hip/hip_runtime.h>

#define T_STEPS 8192
#define BATCH   128
#define HID     96
#define BT      4                  // batch tile per block
#define NBLK    (BATCH / BT)       // 32 blocks

typedef unsigned int u32;
typedef u32   u32x4 __attribute__((ext_vector_type(4)));
typedef float f32x4 __attribute__((ext_vector_type(4)));
typedef __fp16 h2_t __attribute__((ext_vector_type(2)));

#define L2E 1.4426950408889634f
#define K2  2.8853900817779268f   // 2*log2(e)

__device__ __forceinline__ u32 pk2(float a, float b) {
    return __builtin_bit_cast(u32, __builtin_amdgcn_cvt_pkrtz(a, b));
}
__device__ __forceinline__ float fdot2u(u32 w, u32 h, float acc) {
    return __builtin_amdgcn_fdot2(__builtin_bit_cast(h2_t, w),
                                  __builtin_bit_cast(h2_t, h), acc, false);
}
// preacts arrive PRE-SCALED by log2e (2log2e for g/cell): exp2 direct, no mul
__device__ __forceinline__ float sig2(float v) {
    return __builtin_amdgcn_rcpf(1.0f + __builtin_amdgcn_exp2f(-v));
}
__device__ __forceinline__ float tanh2(float v) {
    return fmaf(2.0f, __builtin_amdgcn_rcpf(1.0f + __builtin_amdgcn_exp2f(-v)), -1.0f);
}

#define MFMA(ACC, AF, BF) \
    asm("v_mfma_f32_16x16x32_f16 %0, %1, %2, %0" : "+v"(ACC) : "v"(AF), "a"(BF))

// LDS-only barrier (R15/R16-proven)
#define LBAR() asm volatile("s_waitcnt lgkmcnt(0)\n\ts_barrier" ::: "memory")

// ---- prepack W_hh -> f16 MFMA B-frags (R12-verified mapping) + exp2 prescale ----
__global__ void prepack_kernel(const float* __restrict__ W_hh, u32* __restrict__ wpk) {
    const int i = blockIdx.x * blockDim.x + threadIdx.x;
    if (i < 384 * 48) {
        const int r   = i & 3;
        const int u4  = i >> 2;
        const int tid = u4 / 12;
        const int f   = u4 % 12;
        const int g = f / 3, s = f % 3;
        const int l = tid & 63, u = tid >> 6;
        const int n = g * HID + u * 16 + (l & 15);
        const int k = s * 32 + ((l >> 4) & 3) * 8 + 2 * r;
        const float sc = (g == 2) ? K2 : L2E;
        wpk[i] = pk2(W_hh[n * HID + k] * sc, W_hh[n * HID + k + 1] * sc);
    }
}

__global__ __attribute__((amdgpu_flat_work_group_size(448, 448), amdgpu_waves_per_eu(1, 2)))
void lstm_mfma_kernel(const float* __restrict__ x,
                      const float* __restrict__ W_ih,
                      const float* __restrict__ b_ih,
                      const float* __restrict__ b_hh,
                      const float* __restrict__ W_fc,
                      const float* __restrict__ b_fc,
                      const u32x4* __restrict__ wpk4,
                      float* __restrict__ out)
{
    const int bo  = blockIdx.x * BT;
    const int tid = threadIdx.x;            // waves 0-5 workers, wave 6 FC
    const int l = tid & 63, u = tid >> 6;
    const bool isW = tid < 384;
    const int lg = l >> 4;                  // k-subgroup / epilogue batch

    __shared__ __align__(16) __fp16 hbuf[2][BT][104];   // h state, row-pad 104
    __shared__ __align__(16) float  xs[2][BT];

    for (int i = tid; i < 2 * BT * 104 / 2; i += 448) ((u32*)hbuf)[i] = 0u;
    if (tid < BT) xs[0][tid] = x[bo + tid];

    const int jw = isW ? (u * 16 + (l & 15)) : 0;

    // B-frags: load once, pin to AGPRs (R12-proven residency, FETCH ~4.4MB/blk-set)
    const u32x4* wp = wpk4 + (isW ? tid * 12 : 0);
    u32x4 b0 = wp[0], b1 = wp[1], b2  = wp[2],  b3  = wp[3];
    u32x4 b4 = wp[4], b5 = wp[5], b6  = wp[6],  b7  = wp[7];
    u32x4 b8 = wp[8], b9 = wp[9], b10 = wp[10], b11 = wp[11];
    asm volatile("" : "+a"(b0));  asm volatile("" : "+a"(b1));
    asm volatile("" : "+a"(b2));  asm volatile("" : "+a"(b3));
    asm volatile("" : "+a"(b4));  asm volatile("" : "+a"(b5));
    asm volatile("" : "+a"(b6));  asm volatile("" : "+a"(b7));
    asm volatile("" : "+a"(b8));  asm volatile("" : "+a"(b9));
    asm volatile("" : "+a"(b10)); asm volatile("" : "+a"(b11));

    // x-weights / biases, prescaled per gate (i,f,o: log2e; g: 2log2e)
    f32x4 wih4 = { W_ih[0*HID+jw] * L2E, W_ih[1*HID+jw] * L2E,
                   W_ih[2*HID+jw] * K2,  W_ih[3*HID+jw] * L2E };
    f32x4 bs4  = { (b_ih[0*HID+jw] + b_hh[0*HID+jw]) * L2E,
                   (b_ih[1*HID+jw] + b_hh[1*HID+jw]) * L2E,
                   (b_ih[2*HID+jw] + b_hh[2*HID+jw]) * K2,
                   (b_ih[3*HID+jw] + b_hh[3*HID+jw]) * L2E };
    asm volatile("" : "+v"(wih4)); asm volatile("" : "+v"(bs4));
    const float bfc = b_fc[0];

    // FC wave: fm = l&3 (batch), fp = l>>2 (16 groups x 6 f16 cols)
    const int fm = l & 3, fp = l >> 2;
    u32 wf0 = 0, wf1 = 0, wf2 = 0;
    if (!isW) {
        wf0 = pk2(W_fc[fp*6+0], W_fc[fp*6+1]);
        wf1 = pk2(W_fc[fp*6+2], W_fc[fp*6+3]);
        wf2 = pk2(W_fc[fp*6+4], W_fc[fp*6+5]);
    }

    float c = 0.0f;                         // scaled cell state, batch lg, unit jw

    // FC x shift-chain: xO=x[t-1], xC=x[t], xP=x[t+1]
    float xO = 0.f, xC = 0.f, xP = 0.f;
    if (!isW) { xC = x[bo + fm]; xP = x[BATCH + bo + fm]; }
    __syncthreads();

    for (int t = 0; t < T_STEPS; ++t) {
        const int cb = t & 1, nb = cb ^ 1;
        if (isW) {
            const float xm = xs[cb][lg];    // this lane's batch x (broadcast read)
            // A-frags: lane l holds A[row l&15][k=lg*8+e]; rowbatch(rho)=rho>>2
            const __fp16* hrow = &hbuf[cb][(l & 15) >> 2][lg * 8];
            const u32x4 a0 = *(const u32x4*)(hrow);
            const u32x4 a1 = *(const u32x4*)(hrow + 32);
            const u32x4 a2 = *(const u32x4*)(hrow + 64);

            // C-init: all 4 acc rows = batch lg -> splat e_g
            const float e0 = fmaf(xm, wih4[0], bs4[0]);
            const float e1 = fmaf(xm, wih4[1], bs4[1]);
            const float e2 = fmaf(xm, wih4[2], bs4[2]);
            const float e3 = fmaf(xm, wih4[3], bs4[3]);
            f32x4 acc0 = {e0, e0, e0, e0};
            f32x4 acc1 = {e1, e1, e1, e1};
            f32x4 acc2 = {e2, e2, e2, e2};
            f32x4 acc3 = {e3, e3, e3, e3};

            MFMA(acc0, a0, b0); MFMA(acc1, a0, b3); MFMA(acc2, a0, b6); MFMA(acc3, a0, b9);
            MFMA(acc0, a1, b1); MFMA(acc1, a1, b4); MFMA(acc2, a1, b7); MFMA(acc3, a1, b10);
            MFMA(acc0, a2, b2); MFMA(acc1, a2, b5); MFMA(acc2, a2, b8); MFMA(acc3, a2, b11);
            asm volatile("s_nop 7\n\ts_nop 7");     // MFMA->VALU hazard guard

            // epilogue: ONE update per lane (batch lg, unit jw), static reg index 0
            const float gi = sig2(acc0[0]);
            const float gf = sig2(acc1[0]);
            const float gg = tanh2(acc2[0]);
            const float go = sig2(acc3[0]);
            c = fmaf(gf, c, gi * gg * K2);
            const float hn = go * tanh2(c);
            hbuf[nb][lg][jw] = (__fp16)hn;
        } else {
            if (t > 0) {
                // h_t dot W_fc: lane (fm, fp) covers 6 f16 cols
                const u32* hp = (const u32*)&hbuf[cb][fm][0] + fp * 3;
                const u32 hA = hp[0], hB = hp[1], hC = hp[2];
                float s0 = fdot2u(wf0, hA, 0.0f);
                float s1 = fdot2u(wf1, hB, 0.0f);
                float s2 = fdot2u(wf2, hC, 0.0f);
                float s = (s0 + s1) + s2;
                s += __shfl_xor(s, 4); s += __shfl_xor(s, 8);
                s += __shfl_xor(s, 16); s += __shfl_xor(s, 32);
                if (fp == 0) out[(t - 1) * BATCH + bo + fm] = s + bfc + xO;  // fire-and-forget
            }
            if (fp == 0) xs[nb][fm] = xP;           // stage x[t+1]
            xO = xC; xC = xP;                       // shift chain
            const int tn = (t + 2 < T_STEPS) ? (t + 2) : (T_STEPS - 1);
            xP = x[tn * BATCH + bo + fm];
        }
        LBAR();
    }

    if (!isW) {   // tail: out[T-1] from h_T (hbuf[0]); xO = x[T-1]
        const u32* hp = (const u32*)&hbuf[T_STEPS & 1][fm][0] + fp * 3;
        const u32 hA = hp[0], hB = hp[1], hC = hp[2];
        float s0 = fdot2u(wf0, hA, 0.0f);
        float s1 = fdot2u(wf1, hB, 0.0f);
        float s2 = fdot2u(wf2, hC, 0.0f);
        float s = (s0 + s1) + s2;
        s += __shfl_xor(s, 4); s += __shfl_xor(s, 8);
        s += __shfl_xor(s, 16); s += __shfl_xor(s, 32);
        if (fp == 0) out[(T_STEPS - 1) * BATCH + bo + fm] = s + bfc + xO;
    }
}

extern "C" void kernel_launch(void* const* d_in, const int* in_sizes, int n_in,
                              void* d_out, int out_size, void* d_ws, size_t ws_size,
                              hipStream_t stream) {
    (void)in_sizes; (void)n_in; (void)out_size; (void)ws_size;
    const float* x    = (const float*)d_in[0];
    const float* W_ih = (const float*)d_in[1];
    const float* W_hh = (const float*)d_in[2];
    const float* b_ih = (const float*)d_in[3];
    const float* b_hh = (const float*)d_in[4];
    const float* W_fc = (const float*)d_in[5];
    const float* b_fc = (const float*)d_in[6];
    float* out = (float*)d_out;
    u32* wpk = (u32*)d_ws;                          // 384*48 u32 = 73728 B

    prepack_kernel<<<dim3((384 * 48 + 255) / 256), dim3(256), 0, stream>>>(W_hh, wpk);

    lstm_mfma_kernel<<<dim3(NBLK), dim3(448), 0, stream>>>(
        x, W_ih, b_ih, b_hh, W_fc, b_fc, (const u32x4*)wpk, out);
}